// Round 18
// baseline (104.204 us; speedup 1.0000x reference)
//
#include <hip/hip_runtime.h>
#include <hip/hip_bf16.h>
#include <math.h>

// S4D via chunked state-passing (SSD-style), MFMA formulation, double-bf16 (hi/lo).
// ROUND-18: main kernel BYTE-IDENTICAL to R17 (proven best: main ~89us, absmax
// 0.03125, DMA table staging). Only change: K1 v5 — Kd ownership split so each
// of the 8 sub-blocks computes only its own d-range [8s,8s+8) (8x fewer
// transcendentals), with Tk written along owned diagonals (values bit-identical;
// upper-triangle zeros covered; pads never read by K2).
//
//   E_c[p]   = sum_j Win[p][j] u[cT+j]                (MFMA)
//   S_{c+1}  = lam^T S_c + E_c                        (fp32 scan, 1 wave/seq)
//   y[cT+j]  = (U x Toeplitz(K))[c][j]                (MFMA)
//            + (S x WoutT)[c][j]                      (MFMA)
//            + D u[cT+j]                              (exact fp32)
// Each matmul: Xhi*Whi + Xlo*Whi + Xhi*Wlo (3 MFMAs) -> ~fp32 accuracy.

#define B_ 16
#define H_ 256
#define L_ 4096

typedef __attribute__((ext_vector_type(8))) short short8;
typedef __attribute__((ext_vector_type(4))) float f32x4;

#define WIN_STRIDE 72    // [128][72] ushort per plane : Win stored [p][j]
#define TK_STRIDE  72    // [64][72]                    : Tk  stored [j][m] = K[j-m]
#define WOUT_STRIDE 136  // [64][136]                   : Wout stored [j][p]

#define WIN_ELEMS  (128 * WIN_STRIDE)   // 9216  = 8 * 1152
#define TK_ELEMS   (64 * TK_STRIDE)     // 4608
#define WOUT_ELEMS (64 * WOUT_STRIDE)   // 8704  = 8 * 1088

#define WIN_BYTES  (2 * WIN_ELEMS * 2)   // 36864 B
#define TK_BYTES   (2 * TK_ELEMS * 2)    // 18432 B
#define WOUT_BYTES (2 * WOUT_ELEMS * 2)  // 34816 B

__device__ __forceinline__ unsigned short f2bf(float f) {
    unsigned int u = __float_as_uint(f);
    u = (u + 0x7FFFu + ((u >> 16) & 1u)) >> 16;   // RNE
    return (unsigned short)u;
}
__device__ __forceinline__ float bf2f(unsigned short h) {
    return __uint_as_float(((unsigned int)h) << 16);
}
__device__ __forceinline__ void split2(float v, short& hi, short& lo) {
    unsigned short h = f2bf(v);
    hi = (short)h;
    lo = (short)f2bf(v - bf2f(h));
}
// 16B global->LDS DMA: LDS dest is wave-uniform base (+ lane*16 by HW),
// global src is per-lane.
__device__ __forceinline__ void gld16(const void* g, void* l) {
    __builtin_amdgcn_global_load_lds(
        (const __attribute__((address_space(1))) unsigned int*)g,
        (__attribute__((address_space(3))) unsigned int*)l, 16, 0, 0);
}

// ---------------- K1 v5: per-h tables, 8 sub-blocks per h, Kd-ownership split ----------------
__global__ __launch_bounds__(256) void s4d_tables(
    const float* __restrict__ A_re, const float* __restrict__ A_im,
    const float* __restrict__ C,    const float* __restrict__ log_step,
    unsigned short* __restrict__ win_g, unsigned short* __restrict__ tk_g,
    unsigned short* __restrict__ wout_g, float* __restrict__ lamT_g)
{
    // XCD pinning (bijective over 2048 blocks): xcd = bid&7, h = xcd*32 + (bid>>6),
    // sub = (bid>>3)&7. Each (h,sub) occurs exactly once.
    const int bid0 = blockIdx.x;
    const int h   = (bid0 & 7) * 32 + (bid0 >> 6);
    const int sub = (bid0 >> 3) & 7;
    const int tid = threadIdx.x;
    __shared__ float pr[64], pi[64], cr_[64], ci_[64], Kd8[8];
    __shared__ float kpart[4][8];
    const float step = expf(log_step[h]);

    if (tid < 64) {
        int n = tid;
        float are = fminf(A_re[h * 64 + n], -1e-4f);
        float aim = A_im[h * 64 + n];
        float dre = step * are, dim = step * aim;
        float er = expf(dre);
        float l1r = er * cosf(dim), l1i = er * sinf(dim);
        float inv = 1.0f / (are * are + aim * aim);
        float nre = l1r - 1.0f, nim = l1i;
        float qre = (nre * are + nim * aim) * inv;
        float qim = (nim * are - nre * aim) * inv;
        float c0 = C[(h * 64 + n) * 2], c1 = C[(h * 64 + n) * 2 + 1];
        pr[n] = dre; pi[n] = dim;
        cr_[n] = c0 * qre - c1 * qim;
        ci_[n] = c0 * qim + c1 * qre;
        if (sub == 0) {
            float m = expf(64.0f * dre);
            lamT_g[(h * 64 + n) * 2]     = m * cosf(64.0f * dim);
            lamT_g[(h * 64 + n) * 2 + 1] = m * sinf(64.0f * dim);
        }
    }
    __syncthreads();

    // ---- Kd partials for OWNED d-range only: d = sub*8 + (tid&7), q = tid>>3 ----
    // Same 4-way n-grouping and order as the proven R12/R16 build -> bit-identical.
    if (tid < 32) {
        const int dd = tid & 7, q = tid >> 3;
        const int d = sub * 8 + dd;
        float acc = 0.f;
        for (int n = q * 16; n < q * 16 + 16; ++n) {
            float m = expf((float)d * pr[n]);
            float a = (float)d * pi[n];
            acc += m * (cr_[n] * cosf(a) - ci_[n] * sinf(a));
        }
        kpart[q][dd] = acc;
    }
    __syncthreads();
    if (tid < 8)
        Kd8[tid] = ((kpart[0][tid] + kpart[1][tid]) + kpart[2][tid]) + kpart[3][tid];

    // ---- Win eighth: i in [sub*1152, (sub+1)*1152) (unchanged) ----
    unsigned short* winH = win_g + (size_t)h * (2 * WIN_ELEMS);
    unsigned short* winL = winH + WIN_ELEMS;
    for (int i = sub * 1152 + tid; i < (sub + 1) * 1152; i += 256) {
        int p = i / WIN_STRIDE, j = i - p * WIN_STRIDE;
        float v = 0.f;
        if (j < 64) {
            int n = p & 63;
            float e = (float)(63 - j);
            float m = expf(e * pr[n]), a = e * pi[n];
            v = (p < 64) ? m * cosf(a) : m * sinf(a);
        }
        unsigned short hv = f2bf(v);
        winH[i] = hv;
        winL[i] = f2bf(v - bf2f(hv));
    }

    // ---- Wout eighth: i in [sub*1088, (sub+1)*1088) (unchanged) ----
    unsigned short* woH = wout_g + (size_t)h * (2 * WOUT_ELEMS);
    unsigned short* woL = woH + WOUT_ELEMS;
    for (int i = sub * 1088 + tid; i < (sub + 1) * 1088; i += 256) {
        int j = i / WOUT_STRIDE, p = i - j * WOUT_STRIDE;
        float v = 0.f;
        if (p < 128) {
            int n = p & 63;
            float e = (float)(j + 1);
            float m = expf(e * pr[n]), a = e * pi[n];
            float lr = m * cosf(a), li = m * sinf(a);
            float wr = cr_[n] * lr - ci_[n] * li;
            float wi = cr_[n] * li + ci_[n] * lr;
            v = (p < 64) ? wr : -wi;
        }
        unsigned short hv = f2bf(v);
        woH[i] = hv;
        woL[i] = f2bf(v - bf2f(hv));
    }
    __syncthreads();   // Kd8 visible to all

    // ---- Tk along owned diagonals ----
    // Value diagonals: d = sub*8+dd, element (j, m=j-d) for j in [d,64):
    //   tk[j][j-d] = f2bf(Kd[d])  (bit-identical to the full-Kd build).
    // Zero diagonals: dneg = sub*8+dd >= 1, element (j, m=j+dneg) for m<64.
    // Pads m in [64,72) are never read by K2 (reads cover m<64 only) -> skipped.
    unsigned short* tkH = tk_g + (size_t)h * (2 * TK_ELEMS);
    unsigned short* tkL = tkH + TK_ELEMS;
    for (int idx = tid; idx < 512; idx += 256) {
        int dd = idx >> 6, j = idx & 63;
        int d = sub * 8 + dd;
        if (j >= d) {
            float v = Kd8[dd];
            unsigned short hv = f2bf(v);
            int i = j * TK_STRIDE + (j - d);
            tkH[i] = hv;
            tkL[i] = f2bf(v - bf2f(hv));
        }
    }
    for (int idx = tid; idx < 512; idx += 256) {
        int dd = idx >> 6, j = idx & 63;
        int dneg = sub * 8 + dd;
        int m = j + dneg;
        if (dneg >= 1 && m < 64) {
            int i = j * TK_STRIDE + m;
            tkH[i] = f2bf(0.f);
            tkL[i] = f2bf(0.f);
        }
    }
}

// ---------------- K2: main (two sequences per block) — BYTE-IDENTICAL to R17 ----------------
__global__ __launch_bounds__(512, 1) void s4d_main(
    const float* __restrict__ u, const float* __restrict__ D,
    const unsigned short* __restrict__ win_g, const unsigned short* __restrict__ tk_g,
    const unsigned short* __restrict__ wout_g, const float* __restrict__ lamT_g,
    float* __restrict__ y)
{
    const int tid  = threadIdx.x;
    const int lane = tid & 63, w = tid >> 6;   // w in [0,8)
    const int wg   = w >> 2, ww = w & 3;       // wave-group (sequence) / role
    const int l15  = lane & 15;

    // XCD-pinned bijection: 8 blocks per h on one XCD; block handles b=bp and b=bp+8.
    const int bid  = blockIdx.x;
    const int xcd  = bid & 7, slot = bid >> 3;     // slot in [0,256)
    const int h  = xcd * 32 + (slot >> 3);
    const int bp = slot & 7;
    const size_t ubase0 = ((size_t)bp * H_ + h) * (size_t)L_;
    const size_t ubase1 = ((size_t)(bp + 8) * H_ + h) * (size_t)L_;

    __shared__ __align__(16) float u_lds[2][64][68];               // 34816 B
    __shared__ __align__(16) float ES[2][64][132];                 // 67584 B
    __shared__ __align__(16) unsigned short bufB[2 * (WIN_ELEMS + TK_ELEMS)];  // 55296 B
    unsigned short* winB  = bufB;                       // [2][WIN_ELEMS] hi,lo
    unsigned short* tkB   = bufB + 2 * WIN_ELEMS;       // [2][TK_ELEMS]  hi,lo
    unsigned short* woutB = bufB;                       // [2][WOUT_ELEMS] over win (phased)

    // ---- stage Win + Tk via 16B global->LDS DMA (1 KB/wave/inst, no VGPR) ----
    {
        const char* winSrc = (const char*)(win_g + (size_t)h * (2 * WIN_ELEMS));
        const char* tkSrc  = (const char*)(tk_g  + (size_t)h * (2 * TK_ELEMS));
        char* winDst = (char*)winB;
        char* tkDst  = (char*)tkB;
        for (int c = w; c < WIN_BYTES / 1024; c += 8)
            gld16(winSrc + c * 1024 + lane * 16, winDst + c * 1024);
        for (int c = w; c < TK_BYTES / 1024; c += 8)
            gld16(tkSrc + c * 1024 + lane * 16, tkDst + c * 1024);
    }
    // ---- stage u for BOTH sequences (fp32, coalesced; overlaps the DMA) ----
    for (int it = 0; it < 4; ++it) {
        int l = it * 2048 + tid * 4;
        int seq = l >> 12, within = l & 4095;
        const size_t ub = seq ? ubase1 : ubase0;
        float4 v = *(const float4*)&u[ub + within];
        *(float4*)&u_lds[seq][within >> 6][within & 63] = v;
    }
    __syncthreads();   // drains vmcnt (DMA) + lgkmcnt before consume

    const int row  = ww * 16 + l15;          // A row (chunk index) for this wave
    const int koff = (lane >> 4) * 8;        // k sub-offset within fragment

    // ---- A fragments of U (hi/lo bf16) from LDS ----
    short8 auh[2], aul[2];
#pragma unroll
    for (int kb = 0; kb < 2; ++kb) {
        float4 v0 = *(const float4*)&u_lds[wg][row][kb * 32 + koff];
        float4 v1 = *(const float4*)&u_lds[wg][row][kb * 32 + koff + 4];
        float vv[8] = {v0.x, v0.y, v0.z, v0.w, v1.x, v1.y, v1.z, v1.w};
#pragma unroll
        for (int e = 0; e < 8; ++e) { short hi, lo; split2(vv[e], hi, lo); auh[kb][e] = hi; aul[kb][e] = lo; }
    }

    // ---- phase 1a: E = U x WinT (3-term hi/lo) ----
    for (int nt = 0; nt < 8; ++nt) {
        f32x4 acc = {0.f, 0.f, 0.f, 0.f};
#pragma unroll
        for (int kb = 0; kb < 2; ++kb) {
            const int boff = (nt * 16 + l15) * WIN_STRIDE + kb * 32 + koff;
            short8 bh = *(const short8*)&winB[boff];
            short8 bl = *(const short8*)&winB[WIN_ELEMS + boff];
            acc = __builtin_amdgcn_mfma_f32_16x16x32_bf16(auh[kb], bh, acc, 0, 0, 0);
            acc = __builtin_amdgcn_mfma_f32_16x16x32_bf16(aul[kb], bh, acc, 0, 0, 0);
            acc = __builtin_amdgcn_mfma_f32_16x16x32_bf16(auh[kb], bl, acc, 0, 0, 0);
        }
#pragma unroll
        for (int r = 0; r < 4; ++r)
            ES[wg][ww * 16 + (lane >> 4) * 4 + r][nt * 16 + l15] = acc[r];
    }

    // ---- phase 1b: Y2 = U x TkT (3-term hi/lo), kept in regs ----
    f32x4 yacc[4];
    for (int nt = 0; nt < 4; ++nt) {
        f32x4 acc = {0.f, 0.f, 0.f, 0.f};
#pragma unroll
        for (int kb = 0; kb < 2; ++kb) {
            const int boff = (nt * 16 + l15) * TK_STRIDE + kb * 32 + koff;
            short8 bh = *(const short8*)&tkB[boff];
            short8 bl = *(const short8*)&tkB[TK_ELEMS + boff];
            acc = __builtin_amdgcn_mfma_f32_16x16x32_bf16(auh[kb], bh, acc, 0, 0, 0);
            acc = __builtin_amdgcn_mfma_f32_16x16x32_bf16(aul[kb], bh, acc, 0, 0, 0);
            acc = __builtin_amdgcn_mfma_f32_16x16x32_bf16(auh[kb], bl, acc, 0, 0, 0);
        }
        yacc[nt] = acc;
    }
    __syncthreads();

    // ---- phase 2: wave 0 of each group scans its ES (fp32); other 6 waves stage Wout ----
    if (ww == 0) {
        float ltr = lamT_g[(h * 64 + lane) * 2];
        float lti = lamT_g[(h * 64 + lane) * 2 + 1];
        float sr = 0.f, si = 0.f;
#pragma unroll 8
        for (int c = 0; c < 64; ++c) {
            float er = ES[wg][c][lane], ei = ES[wg][c][lane + 64];
            ES[wg][c][lane] = sr; ES[wg][c][lane + 64] = si;   // store PRE-state S_c
            float nsr = ltr * sr - lti * si + er;
            si = ltr * si + lti * sr + ei;
            sr = nsr;
        }
    } else {
        const char* woSrc = (const char*)(wout_g + (size_t)h * (2 * WOUT_ELEMS));
        char* woDst = (char*)woutB;
        const int sidx = wg * 3 + (ww - 1);    // 0..5 over the 6 staging waves
        for (int c = sidx; c < WOUT_BYTES / 1024; c += 6)
            gld16(woSrc + c * 1024 + lane * 16, woDst + c * 1024);
    }
    __syncthreads();   // drains wout DMA

    // ---- phase 3: Y1 = S x WoutT (3-term hi/lo), K = 128 ----
    for (int kb = 0; kb < 4; ++kb) {
        float4 v0 = *(const float4*)&ES[wg][row][kb * 32 + koff];
        float4 v1 = *(const float4*)&ES[wg][row][kb * 32 + koff + 4];
        float vv[8] = {v0.x, v0.y, v0.z, v0.w, v1.x, v1.y, v1.z, v1.w};
        short8 ash, asl;
#pragma unroll
        for (int e = 0; e < 8; ++e) { short hi, lo; split2(vv[e], hi, lo); ash[e] = hi; asl[e] = lo; }
#pragma unroll
        for (int nt = 0; nt < 4; ++nt) {
            const int boff = (nt * 16 + l15) * WOUT_STRIDE + kb * 32 + koff;
            short8 bh = *(const short8*)&woutB[boff];
            short8 bl = *(const short8*)&woutB[WOUT_ELEMS + boff];
            yacc[nt] = __builtin_amdgcn_mfma_f32_16x16x32_bf16(ash, bh, yacc[nt], 0, 0, 0);
            yacc[nt] = __builtin_amdgcn_mfma_f32_16x16x32_bf16(asl, bh, yacc[nt], 0, 0, 0);
            yacc[nt] = __builtin_amdgcn_mfma_f32_16x16x32_bf16(ash, bl, yacc[nt], 0, 0, 0);
        }
    }
    __syncthreads();           // everyone done reading ES

    // ---- write y tiles into ES ----
#pragma unroll
    for (int nt = 0; nt < 4; ++nt)
#pragma unroll
        for (int r = 0; r < 4; ++r)
            ES[wg][ww * 16 + (lane >> 4) * 4 + r][nt * 16 + l15] = yacc[nt][r];
    __syncthreads();

    // ---- epilogue: y = Y + D*u (exact fp32), both sequences, coalesced float4 ----
    const float Dh = D[h];
    for (int it = 0; it < 4; ++it) {
        int l = it * 2048 + tid * 4;
        int seq = l >> 12, within = l & 4095;
        int c = within >> 6, j = within & 63;
        float4 yv = *(const float4*)&ES[seq][c][j];
        float4 uv = *(const float4*)&u_lds[seq][c][j];
        float4 o;
        o.x = yv.x + Dh * uv.x; o.y = yv.y + Dh * uv.y;
        o.z = yv.z + Dh * uv.z; o.w = yv.w + Dh * uv.w;
        *(float4*)&y[(seq ? ubase1 : ubase0) + within] = o;
    }
}

extern "C" void kernel_launch(void* const* d_in, const int* in_sizes, int n_in,
                              void* d_out, int out_size, void* d_ws, size_t ws_size,
                              hipStream_t stream) {
    const float* u        = (const float*)d_in[0];
    const float* A_re     = (const float*)d_in[1];
    const float* A_im     = (const float*)d_in[2];
    const float* C        = (const float*)d_in[3];
    const float* D        = (const float*)d_in[4];
    const float* log_step = (const float*)d_in[5];
    float* y = (float*)d_out;

    // workspace layout (bytes) — EXACT round-3/8/9/11/12/14/16/17
    char* ws = (char*)d_ws;
    unsigned short* win_g  = (unsigned short*)(ws);               //  9,437,184 B
    unsigned short* tk_g   = (unsigned short*)(ws + 9437184);     //  4,718,592 B
    unsigned short* wout_g = (unsigned short*)(ws + 14155776);    //  8,912,896 B
    float*          lamT_g = (float*)(ws + 23068672);             //    131,072 B

    s4d_tables<<<H_ * 8, 256, 0, stream>>>(A_re, A_im, C, log_step, win_g, tk_g, wout_g, lamT_g);
    s4d_main<<<(B_ * H_) / 2, 512, 0, stream>>>(u, D, win_g, tk_g, wout_g, lamT_g, y);
}

// Round 19
// 102.540 us; speedup vs baseline: 1.0162x; 1.0162x over previous
//
#include <hip/hip_runtime.h>
#include <hip/hip_bf16.h>
#include <math.h>

// S4D via chunked state-passing (SSD-style), MFMA formulation, double-bf16 (hi/lo).
// ROUND-19 (FINAL): byte-for-byte revert to the ROUND-17 session optimum
// (total 102.8us, main ~89us, absmax 0.03125). R18's Kd-ownership split was
// neutral; K1 overhead is at its empirical floor. Main kernel's remaining
// headroom (latency-bound, 21% occupancy) is gated by the session correctness
// law: 5/5 MFMA-phase staging rewrites fail at ~0.33-0.38; producer-class
// changes (R15 compute-in-LDS, R17 DMA staging) pass. 227us -> 102.8us (2.2x).
//
//   E_c[p]   = sum_j Win[p][j] u[cT+j]                (MFMA)
//   S_{c+1}  = lam^T S_c + E_c                        (fp32 scan, 1 wave/seq)
//   y[cT+j]  = (U x Toeplitz(K))[c][j]                (MFMA)
//            + (S x WoutT)[c][j]                      (MFMA)
//            + D u[cT+j]                              (exact fp32)
// Each matmul: Xhi*Whi + Xlo*Whi + Xhi*Wlo (3 MFMAs) -> ~fp32 accuracy.

#define B_ 16
#define H_ 256
#define L_ 4096

typedef __attribute__((ext_vector_type(8))) short short8;
typedef __attribute__((ext_vector_type(4))) float f32x4;

#define WIN_STRIDE 72    // [128][72] ushort per plane : Win stored [p][j]
#define TK_STRIDE  72    // [64][72]                    : Tk  stored [j][m] = K[j-m]
#define WOUT_STRIDE 136  // [64][136]                   : Wout stored [j][p]

#define WIN_ELEMS  (128 * WIN_STRIDE)   // 9216  = 8 * 1152
#define TK_ELEMS   (64 * TK_STRIDE)     // 4608  = 8 * 576
#define WOUT_ELEMS (64 * WOUT_STRIDE)   // 8704  = 8 * 1088

#define WIN_BYTES  (2 * WIN_ELEMS * 2)   // 36864 B = 36 KB-chunks
#define TK_BYTES   (2 * TK_ELEMS * 2)    // 18432 B = 18 KB-chunks
#define WOUT_BYTES (2 * WOUT_ELEMS * 2)  // 34816 B = 34 KB-chunks

__device__ __forceinline__ unsigned short f2bf(float f) {
    unsigned int u = __float_as_uint(f);
    u = (u + 0x7FFFu + ((u >> 16) & 1u)) >> 16;   // RNE
    return (unsigned short)u;
}
__device__ __forceinline__ float bf2f(unsigned short h) {
    return __uint_as_float(((unsigned int)h) << 16);
}
__device__ __forceinline__ void split2(float v, short& hi, short& lo) {
    unsigned short h = f2bf(v);
    hi = (short)h;
    lo = (short)f2bf(v - bf2f(h));
}
// 16B global->LDS DMA: LDS dest is wave-uniform base (+ lane*16 by HW),
// global src is per-lane.
__device__ __forceinline__ void gld16(const void* g, void* l) {
    __builtin_amdgcn_global_load_lds(
        (const __attribute__((address_space(1))) unsigned int*)g,
        (__attribute__((address_space(3))) unsigned int*)l, 16, 0, 0);
}

// ---------------- K1 v3: per-h tables (hi/lo planes), 8 sub-blocks per h ----------------
__global__ __launch_bounds__(256) void s4d_tables(
    const float* __restrict__ A_re, const float* __restrict__ A_im,
    const float* __restrict__ C,    const float* __restrict__ log_step,
    unsigned short* __restrict__ win_g, unsigned short* __restrict__ tk_g,
    unsigned short* __restrict__ wout_g, float* __restrict__ lamT_g)
{
    // XCD pinning (bijective over 2048 blocks): xcd = bid&7, h = xcd*32 + (bid>>6),
    // sub = (bid>>3)&7. Each (h,sub) occurs exactly once.
    const int bid0 = blockIdx.x;
    const int h   = (bid0 & 7) * 32 + (bid0 >> 6);
    const int sub = (bid0 >> 3) & 7;
    const int tid = threadIdx.x;
    __shared__ float pr[64], pi[64], cr_[64], ci_[64], Kd[64];
    __shared__ float kpart[4][64];
    const float step = expf(log_step[h]);

    if (tid < 64) {
        int n = tid;
        float are = fminf(A_re[h * 64 + n], -1e-4f);
        float aim = A_im[h * 64 + n];
        float dre = step * are, dim = step * aim;
        float er = expf(dre);
        float l1r = er * cosf(dim), l1i = er * sinf(dim);
        float inv = 1.0f / (are * are + aim * aim);
        float nre = l1r - 1.0f, nim = l1i;
        float qre = (nre * are + nim * aim) * inv;
        float qim = (nim * are - nre * aim) * inv;
        float c0 = C[(h * 64 + n) * 2], c1 = C[(h * 64 + n) * 2 + 1];
        pr[n] = dre; pi[n] = dim;
        cr_[n] = c0 * qre - c1 * qim;
        ci_[n] = c0 * qim + c1 * qre;
        if (sub == 0) {
            float m = expf(64.0f * dre);
            lamT_g[(h * 64 + n) * 2]     = m * cosf(64.0f * dim);
            lamT_g[(h * 64 + n) * 2 + 1] = m * sinf(64.0f * dim);
        }
    }
    __syncthreads();

    // ---- parallel Kd: thread (d = tid&63, q = tid>>6) does 16 n's ----
    {
        const int d = tid & 63, q = tid >> 6;
        float acc = 0.f;
        for (int n = q * 16; n < q * 16 + 16; ++n) {
            float m = expf((float)d * pr[n]);
            float a = (float)d * pi[n];
            acc += m * (cr_[n] * cosf(a) - ci_[n] * sinf(a));
        }
        kpart[q][d] = acc;
    }
    __syncthreads();
    if (tid < 64)
        Kd[tid] = ((kpart[0][tid] + kpart[1][tid]) + kpart[2][tid]) + kpart[3][tid];

    // ---- Win eighth: i in [sub*1152, (sub+1)*1152) ----
    unsigned short* winH = win_g + (size_t)h * (2 * WIN_ELEMS);
    unsigned short* winL = winH + WIN_ELEMS;
    for (int i = sub * 1152 + tid; i < (sub + 1) * 1152; i += 256) {
        int p = i / WIN_STRIDE, j = i - p * WIN_STRIDE;
        float v = 0.f;
        if (j < 64) {
            int n = p & 63;
            float e = (float)(63 - j);
            float m = expf(e * pr[n]), a = e * pi[n];
            v = (p < 64) ? m * cosf(a) : m * sinf(a);
        }
        unsigned short hv = f2bf(v);
        winH[i] = hv;
        winL[i] = f2bf(v - bf2f(hv));
    }

    // ---- Wout eighth: i in [sub*1088, (sub+1)*1088) ----
    unsigned short* woH = wout_g + (size_t)h * (2 * WOUT_ELEMS);
    unsigned short* woL = woH + WOUT_ELEMS;
    for (int i = sub * 1088 + tid; i < (sub + 1) * 1088; i += 256) {
        int j = i / WOUT_STRIDE, p = i - j * WOUT_STRIDE;
        float v = 0.f;
        if (p < 128) {
            int n = p & 63;
            float e = (float)(j + 1);
            float m = expf(e * pr[n]), a = e * pi[n];
            float lr = m * cosf(a), li = m * sinf(a);
            float wr = cr_[n] * lr - ci_[n] * li;
            float wi = cr_[n] * li + ci_[n] * lr;
            v = (p < 64) ? wr : -wi;
        }
        unsigned short hv = f2bf(v);
        woH[i] = hv;
        woL[i] = f2bf(v - bf2f(hv));
    }
    __syncthreads();   // Kd visible to all

    // ---- Tk eighth: i in [sub*576, (sub+1)*576) ----
    unsigned short* tkH = tk_g + (size_t)h * (2 * TK_ELEMS);
    unsigned short* tkL = tkH + TK_ELEMS;
    for (int i = sub * 576 + tid; i < (sub + 1) * 576; i += 256) {
        int j = i / TK_STRIDE, m = i - j * TK_STRIDE;
        float v = (m < 64 && m <= j) ? Kd[j - m] : 0.f;
        unsigned short hv = f2bf(v);
        tkH[i] = hv;
        tkL[i] = f2bf(v - bf2f(hv));
    }
}

// ---------------- K2: main (two sequences per block) ----------------
__global__ __launch_bounds__(512, 1) void s4d_main(
    const float* __restrict__ u, const float* __restrict__ D,
    const unsigned short* __restrict__ win_g, const unsigned short* __restrict__ tk_g,
    const unsigned short* __restrict__ wout_g, const float* __restrict__ lamT_g,
    float* __restrict__ y)
{
    const int tid  = threadIdx.x;
    const int lane = tid & 63, w = tid >> 6;   // w in [0,8)
    const int wg   = w >> 2, ww = w & 3;       // wave-group (sequence) / role
    const int l15  = lane & 15;

    // XCD-pinned bijection: 8 blocks per h on one XCD; block handles b=bp and b=bp+8.
    const int bid  = blockIdx.x;
    const int xcd  = bid & 7, slot = bid >> 3;     // slot in [0,256)
    const int h  = xcd * 32 + (slot >> 3);
    const int bp = slot & 7;
    const size_t ubase0 = ((size_t)bp * H_ + h) * (size_t)L_;
    const size_t ubase1 = ((size_t)(bp + 8) * H_ + h) * (size_t)L_;

    __shared__ __align__(16) float u_lds[2][64][68];               // 34816 B
    __shared__ __align__(16) float ES[2][64][132];                 // 67584 B
    __shared__ __align__(16) unsigned short bufB[2 * (WIN_ELEMS + TK_ELEMS)];  // 55296 B
    unsigned short* winB  = bufB;                       // [2][WIN_ELEMS] hi,lo
    unsigned short* tkB   = bufB + 2 * WIN_ELEMS;       // [2][TK_ELEMS]  hi,lo
    unsigned short* woutB = bufB;                       // [2][WOUT_ELEMS] over win (phased)

    // ---- stage Win + Tk via 16B global->LDS DMA (1 KB/wave/inst, no VGPR) ----
    {
        const char* winSrc = (const char*)(win_g + (size_t)h * (2 * WIN_ELEMS));
        const char* tkSrc  = (const char*)(tk_g  + (size_t)h * (2 * TK_ELEMS));
        char* winDst = (char*)winB;
        char* tkDst  = (char*)tkB;
        for (int c = w; c < WIN_BYTES / 1024; c += 8)
            gld16(winSrc + c * 1024 + lane * 16, winDst + c * 1024);
        for (int c = w; c < TK_BYTES / 1024; c += 8)
            gld16(tkSrc + c * 1024 + lane * 16, tkDst + c * 1024);
    }
    // ---- stage u for BOTH sequences (fp32, coalesced; overlaps the DMA) ----
    for (int it = 0; it < 4; ++it) {
        int l = it * 2048 + tid * 4;
        int seq = l >> 12, within = l & 4095;
        const size_t ub = seq ? ubase1 : ubase0;
        float4 v = *(const float4*)&u[ub + within];
        *(float4*)&u_lds[seq][within >> 6][within & 63] = v;
    }
    __syncthreads();   // drains vmcnt (DMA) + lgkmcnt before consume

    const int row  = ww * 16 + l15;          // A row (chunk index) for this wave
    const int koff = (lane >> 4) * 8;        // k sub-offset within fragment

    // ---- A fragments of U (hi/lo bf16) from LDS ----
    short8 auh[2], aul[2];
#pragma unroll
    for (int kb = 0; kb < 2; ++kb) {
        float4 v0 = *(const float4*)&u_lds[wg][row][kb * 32 + koff];
        float4 v1 = *(const float4*)&u_lds[wg][row][kb * 32 + koff + 4];
        float vv[8] = {v0.x, v0.y, v0.z, v0.w, v1.x, v1.y, v1.z, v1.w};
#pragma unroll
        for (int e = 0; e < 8; ++e) { short hi, lo; split2(vv[e], hi, lo); auh[kb][e] = hi; aul[kb][e] = lo; }
    }

    // ---- phase 1a: E = U x WinT (3-term hi/lo) ----
    for (int nt = 0; nt < 8; ++nt) {
        f32x4 acc = {0.f, 0.f, 0.f, 0.f};
#pragma unroll
        for (int kb = 0; kb < 2; ++kb) {
            const int boff = (nt * 16 + l15) * WIN_STRIDE + kb * 32 + koff;
            short8 bh = *(const short8*)&winB[boff];
            short8 bl = *(const short8*)&winB[WIN_ELEMS + boff];
            acc = __builtin_amdgcn_mfma_f32_16x16x32_bf16(auh[kb], bh, acc, 0, 0, 0);
            acc = __builtin_amdgcn_mfma_f32_16x16x32_bf16(aul[kb], bh, acc, 0, 0, 0);
            acc = __builtin_amdgcn_mfma_f32_16x16x32_bf16(auh[kb], bl, acc, 0, 0, 0);
        }
#pragma unroll
        for (int r = 0; r < 4; ++r)
            ES[wg][ww * 16 + (lane >> 4) * 4 + r][nt * 16 + l15] = acc[r];
    }

    // ---- phase 1b: Y2 = U x TkT (3-term hi/lo), kept in regs ----
    f32x4 yacc[4];
    for (int nt = 0; nt < 4; ++nt) {
        f32x4 acc = {0.f, 0.f, 0.f, 0.f};
#pragma unroll
        for (int kb = 0; kb < 2; ++kb) {
            const int boff = (nt * 16 + l15) * TK_STRIDE + kb * 32 + koff;
            short8 bh = *(const short8*)&tkB[boff];
            short8 bl = *(const short8*)&tkB[TK_ELEMS + boff];
            acc = __builtin_amdgcn_mfma_f32_16x16x32_bf16(auh[kb], bh, acc, 0, 0, 0);
            acc = __builtin_amdgcn_mfma_f32_16x16x32_bf16(aul[kb], bh, acc, 0, 0, 0);
            acc = __builtin_amdgcn_mfma_f32_16x16x32_bf16(auh[kb], bl, acc, 0, 0, 0);
        }
        yacc[nt] = acc;
    }
    __syncthreads();

    // ---- phase 2: wave 0 of each group scans its ES (fp32); other 6 waves stage Wout ----
    if (ww == 0) {
        float ltr = lamT_g[(h * 64 + lane) * 2];
        float lti = lamT_g[(h * 64 + lane) * 2 + 1];
        float sr = 0.f, si = 0.f;
#pragma unroll 8
        for (int c = 0; c < 64; ++c) {
            float er = ES[wg][c][lane], ei = ES[wg][c][lane + 64];
            ES[wg][c][lane] = sr; ES[wg][c][lane + 64] = si;   // store PRE-state S_c
            float nsr = ltr * sr - lti * si + er;
            si = ltr * si + lti * sr + ei;
            sr = nsr;
        }
    } else {
        const char* woSrc = (const char*)(wout_g + (size_t)h * (2 * WOUT_ELEMS));
        char* woDst = (char*)woutB;
        const int sidx = wg * 3 + (ww - 1);    // 0..5 over the 6 staging waves
        for (int c = sidx; c < WOUT_BYTES / 1024; c += 6)
            gld16(woSrc + c * 1024 + lane * 16, woDst + c * 1024);
    }
    __syncthreads();   // drains wout DMA

    // ---- phase 3: Y1 = S x WoutT (3-term hi/lo), K = 128 ----
    for (int kb = 0; kb < 4; ++kb) {
        float4 v0 = *(const float4*)&ES[wg][row][kb * 32 + koff];
        float4 v1 = *(const float4*)&ES[wg][row][kb * 32 + koff + 4];
        float vv[8] = {v0.x, v0.y, v0.z, v0.w, v1.x, v1.y, v1.z, v1.w};
        short8 ash, asl;
#pragma unroll
        for (int e = 0; e < 8; ++e) { short hi, lo; split2(vv[e], hi, lo); ash[e] = hi; asl[e] = lo; }
#pragma unroll
        for (int nt = 0; nt < 4; ++nt) {
            const int boff = (nt * 16 + l15) * WOUT_STRIDE + kb * 32 + koff;
            short8 bh = *(const short8*)&woutB[boff];
            short8 bl = *(const short8*)&woutB[WOUT_ELEMS + boff];
            yacc[nt] = __builtin_amdgcn_mfma_f32_16x16x32_bf16(ash, bh, yacc[nt], 0, 0, 0);
            yacc[nt] = __builtin_amdgcn_mfma_f32_16x16x32_bf16(asl, bh, yacc[nt], 0, 0, 0);
            yacc[nt] = __builtin_amdgcn_mfma_f32_16x16x32_bf16(ash, bl, yacc[nt], 0, 0, 0);
        }
    }
    __syncthreads();           // everyone done reading ES

    // ---- write y tiles into ES ----
#pragma unroll
    for (int nt = 0; nt < 4; ++nt)
#pragma unroll
        for (int r = 0; r < 4; ++r)
            ES[wg][ww * 16 + (lane >> 4) * 4 + r][nt * 16 + l15] = yacc[nt][r];
    __syncthreads();

    // ---- epilogue: y = Y + D*u (exact fp32), both sequences, coalesced float4 ----
    const float Dh = D[h];
    for (int it = 0; it < 4; ++it) {
        int l = it * 2048 + tid * 4;
        int seq = l >> 12, within = l & 4095;
        int c = within >> 6, j = within & 63;
        float4 yv = *(const float4*)&ES[seq][c][j];
        float4 uv = *(const float4*)&u_lds[seq][c][j];
        float4 o;
        o.x = yv.x + Dh * uv.x; o.y = yv.y + Dh * uv.y;
        o.z = yv.z + Dh * uv.z; o.w = yv.w + Dh * uv.w;
        *(float4*)&y[(seq ? ubase1 : ubase0) + within] = o;
    }
}

extern "C" void kernel_launch(void* const* d_in, const int* in_sizes, int n_in,
                              void* d_out, int out_size, void* d_ws, size_t ws_size,
                              hipStream_t stream) {
    const float* u        = (const float*)d_in[0];
    const float* A_re     = (const float*)d_in[1];
    const float* A_im     = (const float*)d_in[2];
    const float* C        = (const float*)d_in[3];
    const float* D        = (const float*)d_in[4];
    const float* log_step = (const float*)d_in[5];
    float* y = (float*)d_out;

    // workspace layout (bytes) — EXACT round-3/8/9/11/12/14/16/17
    char* ws = (char*)d_ws;
    unsigned short* win_g  = (unsigned short*)(ws);               //  9,437,184 B
    unsigned short* tk_g   = (unsigned short*)(ws + 9437184);     //  4,718,592 B
    unsigned short* wout_g = (unsigned short*)(ws + 14155776);    //  8,912,896 B
    float*          lamT_g = (float*)(ws + 23068672);             //    131,072 B

    s4d_tables<<<H_ * 8, 256, 0, stream>>>(A_re, A_im, C, log_step, win_g, tk_g, wout_g, lamT_g);
    s4d_main<<<(B_ * H_) / 2, 512, 0, stream>>>(u, D, win_g, tk_g, wout_g, lamT_g, y);
}